// Round 5
// baseline (1738.719 us; speedup 1.0000x reference)
//
#include <hip/hip_runtime.h>
#include <math.h>

#define L_LEN 4500
#define T2 128
#define NT2 36    // ceil(4500/128)
#define NTT 141   // ceil(4500/32) for out_k tiles
#define SPL 16    // l-splits for gram_k (64 chunk-streams per n)
#define NCHUNK 1125  // 4500/4

// ---------------- prep: transpose conv2 weights to [cin][g][k] ----------------
__global__ void prep_w2t_k(const float* __restrict__ w2, float* __restrict__ w2t) {
    int i = blockIdx.x * 256 + threadIdx.x;
    if (i < 64 * 64 * 5) {
        int k = i / 320;
        int r = i - k * 320;
        int c = r / 5;
        int g = r - c * 5;
        w2t[(c * 5 + g) * 64 + k] = w2[i];
    }
}

// ---------------- conv1: x (64,1,L) -> h1 (64,64,L), k=7, SAME ----------------
__global__ __launch_bounds__(256) void conv1_k(const float* __restrict__ x,
                                               const float* __restrict__ w1,
                                               float* __restrict__ h1) {
    int n = blockIdx.x >> 6, k = blockIdx.x & 63;
    float w[7];
#pragma unroll
    for (int g = 0; g < 7; ++g) w[g] = w1[k * 7 + g];
    const float* xr = x + (size_t)n * L_LEN;
    float* hr = h1 + ((size_t)n * 64 + k) * L_LEN;
    for (int l = threadIdx.x; l < L_LEN; l += 256) {
        float a = 0.f;
#pragma unroll
        for (int g = 0; g < 7; ++g) {
            int p = l + g - 3;
            if (p >= 0 && p < L_LEN) a += w[g] * xr[p];
        }
        hr[l] = a;
    }
}

// ------- conv2: h1 (64,64,L) -> h2 (64,64,L), k=5, SAME; + sumsq atomics ------
__global__ __launch_bounds__(256) void conv2_k(const float* __restrict__ h1,
                                               const float* __restrict__ w2t,
                                               float* __restrict__ h2,
                                               float* __restrict__ sq) {
    __shared__ float h1s[64][T2 + 4];
    __shared__ float sqred[4][64];
    int n = blockIdx.x / NT2;
    int t = blockIdx.x - n * NT2;
    int l0 = t * T2;
    const float* h1n = h1 + (size_t)n * 64 * L_LEN;
    for (int idx = threadIdx.x; idx < 64 * (T2 + 4); idx += 256) {
        int ci = idx / (T2 + 4);
        int j = idx - ci * (T2 + 4);
        int l = l0 + j - 2;
        h1s[ci][j] = (l >= 0 && l < L_LEN) ? h1n[(size_t)ci * L_LEN + l] : 0.f;
    }
    __syncthreads();
    int k = threadIdx.x & 63;
    int lg = threadIdx.x >> 6;
    int base = lg * 32;
    float acc[32];
#pragma unroll
    for (int m = 0; m < 32; ++m) acc[m] = 0.f;
    for (int ci = 0; ci < 64; ++ci) {
        const float* wr = w2t + ci * 320 + k;
        float w0 = wr[0], w1 = wr[64], w2v = wr[128], w3 = wr[192], w4 = wr[256];
        float v[36];
#pragma unroll
        for (int j = 0; j < 36; ++j) v[j] = h1s[ci][base + j];
#pragma unroll
        for (int m = 0; m < 32; ++m)
            acc[m] += w0 * v[m] + w1 * v[m + 1] + w2v * v[m + 2] + w3 * v[m + 3] + w4 * v[m + 4];
    }
    float s = 0.f;
    float* h2r = h2 + ((size_t)n * 64 + k) * L_LEN;
#pragma unroll
    for (int m = 0; m < 32; ++m) {
        int l = l0 + base + m;
        if (l < L_LEN) { h2r[l] = acc[m]; s += acc[m] * acc[m]; }
    }
    sqred[lg][k] = s;
    __syncthreads();
    if (threadIdx.x < 64) {
        float tot = sqred[0][threadIdx.x] + sqred[1][threadIdx.x] +
                    sqred[2][threadIdx.x] + sqred[3][threadIdx.x];
        atomicAdd(&sq[n * 64 + threadIdx.x], tot);
    }
}

// ---------- scale_k: h2 *= 1/(1+sq[n,k]) in place (squash folded once) -------
__global__ __launch_bounds__(256) void scale_k(float* __restrict__ h2,
                                               const float* __restrict__ sq) {
    int nk = blockIdx.x;
    float inv = 1.f / (1.f + sq[nk]);
    float4* row = (float4*)(h2 + (size_t)nk * L_LEN);
    for (int i = threadIdx.x; i < L_LEN / 4; i += 256) {
        float4 v = row[i];
        v.x *= inv; v.y *= inv; v.z *= inv; v.w *= inv;
        row[i] = v;
    }
}

// H chunk (4 l-positions) from pre-scaled h2; direct global loads (L1 broadcast)
template <bool INTERIOR>
__device__ __forceinline__ void gram_chunk(const float* __restrict__ h2n, int l0,
                                           const float* wreg, float biasc, float* M) {
    float H[32];   // H[i*4+m]
#pragma unroll
    for (int q = 0; q < 32; ++q) H[q] = biasc;
#pragma unroll
    for (int i = 0; i < 8; ++i) {
#pragma unroll
        for (int p = 0; p < 8; ++p) {
            const float* r = h2n + (size_t)(8 * i + p) * L_LEN + l0;
            float rr[6];
            if (INTERIOR) {
                float4 ra = *(const float4*)r;
                rr[0] = r[-1]; rr[1] = ra.x; rr[2] = ra.y; rr[3] = ra.z; rr[4] = ra.w; rr[5] = r[4];
            } else {
#pragma unroll
                for (int m = -1; m <= 4; ++m)
                    rr[m + 1] = (l0 + m >= 0 && l0 + m < L_LEN) ? r[m] : 0.f;
            }
            float w0 = wreg[p * 3], w1 = wreg[p * 3 + 1], w2v = wreg[p * 3 + 2];
#pragma unroll
            for (int m = 0; m < 4; ++m)
                H[i * 4 + m] += w0 * rr[m] + w1 * rr[m + 1] + w2v * rr[m + 2];
        }
    }
    int idx2 = 0;
#pragma unroll
    for (int i = 0; i < 8; ++i)
#pragma unroll
        for (int j = i; j < 8; ++j, ++idx2) {
            float a = 0.f;
#pragma unroll
            for (int m = 0; m < 4; ++m) a += H[i * 4 + m] * H[j * 4 + m];
            M[idx2] += a;
        }
}

// ------ gram_k: NO LDS, NO barriers. c = lane; each wave streams chunks ------
__global__ __launch_bounds__(256) void gram_k(const float* __restrict__ h2,
                                              const float* __restrict__ wA,
                                              const float* __restrict__ bA,
                                              float* __restrict__ Mpart) {
    int n = blockIdx.x / SPL;
    int s = blockIdx.x - n * SPL;
    int c = threadIdx.x & 63;
    int sub = threadIdx.x >> 6;
    int stream = s * 4 + sub;   // 0..63
    float wreg[24];
#pragma unroll
    for (int q = 0; q < 24; ++q) wreg[q] = wA[c * 24 + q];
    float biasc = bA[c];
    const float* h2n = h2 + (size_t)n * 64 * L_LEN;
    float M[36];
#pragma unroll
    for (int q = 0; q < 36; ++q) M[q] = 0.f;

    for (int ci = stream; ci < NCHUNK; ci += 64) {
        int l0 = ci * 4;
        if (ci != 0 && ci != NCHUNK - 1) gram_chunk<true>(h2n, l0, wreg, biasc, M);
        else                             gram_chunk<false>(h2n, l0, wreg, biasc, M);
    }
    // per-(stream) partial write; coeff_k reduces the 64 partials
    float* mp = Mpart + (((size_t)n * 64 + stream) * 64 + c) * 36;
#pragma unroll
    for (int q = 0; q < 9; ++q) {
        float4 v = {M[4 * q], M[4 * q + 1], M[4 * q + 2], M[4 * q + 3]};
        *(float4*)(mp + 4 * q) = v;
    }
}

// ---------- coeff_k: reduce 64 partials, routing math, emit coef[8] ----------
__global__ __launch_bounds__(64) void coeff_k(const float* __restrict__ Mpart,
                                              float* __restrict__ coefb) {
    int n = blockIdx.x;
    int c = threadIdx.x;
    float M[36];
#pragma unroll
    for (int q = 0; q < 36; ++q) M[q] = 0.f;
    for (int s2 = 0; s2 < 64; ++s2) {
        const float* mp = Mpart + (((size_t)n * 64 + s2) * 64 + c) * 36;
#pragma unroll
        for (int q = 0; q < 9; ++q) {
            float4 v = *(const float4*)(mp + 4 * q);
            M[4 * q] += v.x; M[4 * q + 1] += v.y; M[4 * q + 2] += v.z; M[4 * q + 3] += v.w;
        }
    }
    float rs[8];
#pragma unroll
    for (int i = 0; i < 8; ++i) rs[i] = 0.f;
    {
        int idx2 = 0;
#pragma unroll
        for (int i = 0; i < 8; ++i)
#pragma unroll
            for (int j = i; j < 8; ++j, ++idx2) {
                rs[i] += M[idx2];
                if (j > i) rs[j] += M[idx2];
            }
    }
    float sumAll = 0.f;
#pragma unroll
    for (int i = 0; i < 8; ++i) sumAll += rs[i];
    float sqn1 = sumAll * (1.f / 64.f);
    float binv = 1.f / (8.f * (1.f + sqn1));
    float bv[8], mx = -1e30f;
#pragma unroll
    for (int i = 0; i < 8; ++i) { bv[i] = rs[i] * binv; mx = fmaxf(mx, bv[i]); }
    float e[8], se = 0.f;
#pragma unroll
    for (int i = 0; i < 8; ++i) { e[i] = expf(bv[i] - mx); se += e[i]; }
    float sinv = 1.f / se;
    float ci_[8];
#pragma unroll
    for (int i = 0; i < 8; ++i) ci_[i] = e[i] * sinv;
    float sqn2 = 0.f;
    {
        int idx2 = 0;
#pragma unroll
        for (int i = 0; i < 8; ++i)
#pragma unroll
            for (int j = i; j < 8; ++j, ++idx2)
                sqn2 += ((j > i) ? 2.f : 1.f) * ci_[i] * ci_[j] * M[idx2];
    }
    float scale = 1.f / (1.f + sqn2);
#pragma unroll
    for (int i = 0; i < 8; ++i) coefb[((size_t)n * 64 + c) * 8 + i] = ci_[i] * scale;
}

// out helper: 8 l-positions, window [lbase-1, lbase+8], direct global loads
template <bool INTERIOR>
__device__ __forceinline__ void out_chunk(const float* __restrict__ h2n, int lbase,
                                          const float* wreg, float biasc,
                                          const float* coef, float* v) {
#pragma unroll
    for (int m = 0; m < 8; ++m) v[m] = 0.f;
#pragma unroll
    for (int i = 0; i < 8; ++i) {
        float Hi[8];
#pragma unroll
        for (int m = 0; m < 8; ++m) Hi[m] = biasc;
#pragma unroll
        for (int p = 0; p < 8; ++p) {
            const float* r = h2n + (size_t)(8 * i + p) * L_LEN + lbase;
            float rr[10];
            if (INTERIOR) {
                float4 ra = *(const float4*)r;
                float4 rb = *(const float4*)(r + 4);
                rr[0] = r[-1];
                rr[1] = ra.x; rr[2] = ra.y; rr[3] = ra.z; rr[4] = ra.w;
                rr[5] = rb.x; rr[6] = rb.y; rr[7] = rb.z; rr[8] = rb.w;
                rr[9] = r[8];
            } else {
#pragma unroll
                for (int m = -1; m <= 8; ++m)
                    rr[m + 1] = (lbase + m >= 0 && lbase + m < L_LEN) ? r[m] : 0.f;
            }
            float w0 = wreg[p * 3], w1 = wreg[p * 3 + 1], w2v = wreg[p * 3 + 2];
#pragma unroll
            for (int m = 0; m < 8; ++m)
                Hi[m] += w0 * rr[m] + w1 * rr[m + 1] + w2v * rr[m + 2];
        }
        float cw = coef[i];
#pragma unroll
        for (int m = 0; m < 8; ++m) v[m] += cw * Hi[m];
    }
}

// -------- out_k: direct-global input; vout LDS staging for coalesced stores ---
__global__ __launch_bounds__(256) void out_k(const float* __restrict__ h2,
                                             const float* __restrict__ wA,
                                             const float* __restrict__ bA,
                                             const float* __restrict__ coefb,
                                             float* __restrict__ out) {
    __shared__ __align__(16) float vout[64 * 33];   // +1 padding: conflict-free writes
    int n = blockIdx.x / NTT;
    int t = blockIdx.x - n * NTT;
    int l0 = t * 32;
    int c = threadIdx.x & 63;
    int sub = threadIdx.x >> 6;
    int lsub = sub * 8;
    int lbase = l0 + lsub;
    float wreg[24];
#pragma unroll
    for (int q = 0; q < 24; ++q) wreg[q] = wA[c * 24 + q];
    float biasc = bA[c];
    float coef[8];
#pragma unroll
    for (int i = 0; i < 8; ++i) coef[i] = coefb[((size_t)n * 64 + c) * 8 + i];
    const float* h2n = h2 + (size_t)n * 64 * L_LEN;
    if (lbase < L_LEN) {
        float v[8];
        if (lbase != 0 && lbase + 9 <= L_LEN) out_chunk<true>(h2n, lbase, wreg, biasc, coef, v);
        else                                  out_chunk<false>(h2n, lbase, wreg, biasc, coef, v);
#pragma unroll
        for (int m = 0; m < 8; ++m) vout[c * 33 + lsub + m] = v[m];
    }
    __syncthreads();
    // 64 rows x 8 float4 = 512 stores over 2 iterations; 4500 % 4 == 0 guard exact
#pragma unroll
    for (int it = 0; it < 2; ++it) {
        int fidx = threadIdx.x + it * 256;
        int cc = fidx >> 3;
        int qq = fidx & 7;
        int l = l0 + qq * 4;
        if (l < L_LEN)
            *(float4*)(out + ((size_t)n * 64 + cc) * L_LEN + l) =
                *(const float4*)&vout[cc * 33 + qq * 4];
    }
}

extern "C" void kernel_launch(void* const* d_in, const int* in_sizes, int n_in,
                              void* d_out, int out_size, void* d_ws, size_t ws_size,
                              hipStream_t stream) {
    const float* x  = (const float*)d_in[0];
    const float* w1 = (const float*)d_in[1];
    const float* w2 = (const float*)d_in[2];
    const float* wA = (const float*)d_in[3];
    const float* bA = (const float*)d_in[4];
    float* out = (float*)d_out;
    char* ws = (char*)d_ws;
    const size_t HB = (size_t)64 * 64 * L_LEN * 4;   // 73,728,000 B
    float* h1    = (float*)ws;                        // dead after conv2
    float* h2    = (float*)(ws + HB);
    float* sq    = (float*)(ws + 2 * HB);             // 16 KB
    float* w2t   = (float*)(ws + 2 * HB + 16384);     // 80 KB
    float* Mpart = h1;                                // overlay: 64*64*64*36*4 = 37.7 MB
    float* coefb = (float*)(ws + 48 * 1024 * 1024);   // overlay in h1 past Mpart

    hipMemsetAsync(sq, 0, 64 * 64 * sizeof(float), stream);
    prep_w2t_k<<<80, 256, 0, stream>>>(w2, w2t);
    conv1_k<<<4096, 256, 0, stream>>>(x, w1, h1);
    conv2_k<<<64 * NT2, 256, 0, stream>>>(h1, w2t, h2, sq);
    scale_k<<<4096, 256, 0, stream>>>(h2, sq);
    gram_k<<<64 * SPL, 256, 0, stream>>>(h2, wA, bA, Mpart);
    coeff_k<<<64, 64, 0, stream>>>(Mpart, coefb);
    out_k<<<64 * NTT, 256, 0, stream>>>(h2, wA, bA, coefb, out);
}

// Round 6
// 905.435 us; speedup vs baseline: 1.9203x; 1.9203x over previous
//
#include <hip/hip_runtime.h>
#include <math.h>

#define L_LEN 4500
#define T2 128
#define NT2 36    // ceil(4500/128)
#define NTT 141   // ceil(4500/32)
#define SPL 32    // l-splits for gram_k

// ---------------- prep: transpose conv2 weights to [cin][g][k] ----------------
__global__ void prep_w2t_k(const float* __restrict__ w2, float* __restrict__ w2t) {
    int i = blockIdx.x * 256 + threadIdx.x;
    if (i < 64 * 64 * 5) {
        int k = i / 320;
        int r = i - k * 320;
        int c = r / 5;
        int g = r - c * 5;
        w2t[(c * 5 + g) * 64 + k] = w2[i];
    }
}

// ---------------- conv1: x (64,1,L) -> h1 (64,64,L), k=7, SAME ----------------
__global__ __launch_bounds__(256) void conv1_k(const float* __restrict__ x,
                                               const float* __restrict__ w1,
                                               float* __restrict__ h1) {
    int n = blockIdx.x >> 6, k = blockIdx.x & 63;
    float w[7];
#pragma unroll
    for (int g = 0; g < 7; ++g) w[g] = w1[k * 7 + g];
    const float* xr = x + (size_t)n * L_LEN;
    float* hr = h1 + ((size_t)n * 64 + k) * L_LEN;
    for (int l = threadIdx.x; l < L_LEN; l += 256) {
        float a = 0.f;
#pragma unroll
        for (int g = 0; g < 7; ++g) {
            int p = l + g - 3;
            if (p >= 0 && p < L_LEN) a += w[g] * xr[p];
        }
        hr[l] = a;
    }
}

// ------- conv2: h1 (64,64,L) -> h2 (64,64,L), k=5, SAME; + sumsq atomics ------
__global__ __launch_bounds__(256) void conv2_k(const float* __restrict__ h1,
                                               const float* __restrict__ w2t,
                                               float* __restrict__ h2,
                                               float* __restrict__ sq) {
    __shared__ float h1s[64][T2 + 4];
    __shared__ float sqred[4][64];
    int n = blockIdx.x / NT2;
    int t = blockIdx.x - n * NT2;
    int l0 = t * T2;
    const float* h1n = h1 + (size_t)n * 64 * L_LEN;
    for (int idx = threadIdx.x; idx < 64 * (T2 + 4); idx += 256) {
        int ci = idx / (T2 + 4);
        int j = idx - ci * (T2 + 4);
        int l = l0 + j - 2;
        h1s[ci][j] = (l >= 0 && l < L_LEN) ? h1n[(size_t)ci * L_LEN + l] : 0.f;
    }
    __syncthreads();
    int k = threadIdx.x & 63;
    int lg = threadIdx.x >> 6;
    int base = lg * 32;
    float acc[32];
#pragma unroll
    for (int m = 0; m < 32; ++m) acc[m] = 0.f;
    for (int ci = 0; ci < 64; ++ci) {
        const float* wr = w2t + ci * 320 + k;
        float w0 = wr[0], w1 = wr[64], w2v = wr[128], w3 = wr[192], w4 = wr[256];
        float v[36];
#pragma unroll
        for (int j = 0; j < 36; ++j) v[j] = h1s[ci][base + j];
#pragma unroll
        for (int m = 0; m < 32; ++m)
            acc[m] += w0 * v[m] + w1 * v[m + 1] + w2v * v[m + 2] + w3 * v[m + 3] + w4 * v[m + 4];
    }
    float s = 0.f;
    float* h2r = h2 + ((size_t)n * 64 + k) * L_LEN;
#pragma unroll
    for (int m = 0; m < 32; ++m) {
        int l = l0 + base + m;
        if (l < L_LEN) { h2r[l] = acc[m]; s += acc[m] * acc[m]; }
    }
    sqred[lg][k] = s;
    __syncthreads();
    if (threadIdx.x < 64) {
        float tot = sqred[0][threadIdx.x] + sqred[1][threadIdx.x] +
                    sqred[2][threadIdx.x] + sqred[3][threadIdx.x];
        atomicAdd(&sq[n * 64 + threadIdx.x], tot);
    }
}

// ------ gram_k: per (n,s) stream tiles; LDS-staged, division-free indexing ----
// c = tid&63 (lane -> channel, LDS compute-reads wave-broadcast).
// staging: row = tid>>2 (fixed per thread), phase = tid&3, 9 cols at stride 4.
// m=4 per pass keeps H at 32 regs (round-4-proven no-spill shape).
__global__ __launch_bounds__(256) void gram_k(const float* __restrict__ h2,
                                              const float* __restrict__ sq,
                                              const float* __restrict__ wA,
                                              const float* __restrict__ bA,
                                              float* __restrict__ Mpart) {
    __shared__ __align__(16) float hs[64 * 36];   // 9216 B; reused for M reduction
    int n = blockIdx.x >> 5;
    int s = blockIdx.x & 31;
    int c = threadIdx.x & 63;
    int sub = threadIdx.x >> 6;
    int srow = threadIdx.x >> 2;
    int sph = threadIdx.x & 3;
    float inv = 1.f / (1.f + sq[n * 64 + srow]);
    float wreg[24];
#pragma unroll
    for (int q = 0; q < 24; ++q) wreg[q] = wA[c * 24 + q];
    float biasc = bA[c];
    const float* h2r = h2 + ((size_t)n * 64 + srow) * L_LEN;
    float M[36];
#pragma unroll
    for (int q = 0; q < 36; ++q) M[q] = 0.f;

    for (int t = s; t < NTT; t += SPL) {
        int l0 = t * 32;
        __syncthreads();
#pragma unroll
        for (int k = 0; k < 9; ++k) {       // shift/add indexing only
            int j = sph + 4 * k;
            int l = l0 + j - 1;
            hs[srow * 36 + j] = (l >= 0 && l < L_LEN) ? h2r[l] * inv : 0.f;
        }
        __syncthreads();
#pragma unroll
        for (int half = 0; half < 2; ++half) {
            int lsub = half * 16 + sub * 4;
            int lbase = l0 + lsub;           // wave-uniform, multiple of 4
            if (lbase >= L_LEN) continue;
            float H[32];
#pragma unroll
            for (int q = 0; q < 32; ++q) H[q] = biasc;
#pragma unroll
            for (int i = 0; i < 8; ++i) {
#pragma unroll
                for (int p = 0; p < 8; ++p) {
                    const float* r = &hs[(8 * i + p) * 36 + lsub];
                    float4 ra = *(const float4*)r;
                    float2 rc = *(const float2*)(r + 4);
                    float rr[6] = {ra.x, ra.y, ra.z, ra.w, rc.x, rc.y};
                    float w0 = wreg[p * 3], w1 = wreg[p * 3 + 1], w2v = wreg[p * 3 + 2];
#pragma unroll
                    for (int m = 0; m < 4; ++m)
                        H[i * 4 + m] += w0 * rr[m] + w1 * rr[m + 1] + w2v * rr[m + 2];
                }
            }
            int idx2 = 0;
#pragma unroll
            for (int i = 0; i < 8; ++i)
#pragma unroll
                for (int j = i; j < 8; ++j, ++idx2) {
                    float a = 0.f;
#pragma unroll
                    for (int m = 0; m < 4; ++m) a += H[i * 4 + m] * H[j * 4 + m];
                    M[idx2] += a;
                }
        }
    }
    // in-block reduction of the 4 sub-partials through hs (4 barrier rounds)
    __syncthreads();
    if (sub == 0) {
#pragma unroll
        for (int q = 0; q < 36; ++q) hs[c * 36 + q] = M[q];
    }
    __syncthreads();
    if (sub == 1) {
#pragma unroll
        for (int q = 0; q < 36; ++q) hs[c * 36 + q] += M[q];
    }
    __syncthreads();
    if (sub == 2) {
#pragma unroll
        for (int q = 0; q < 36; ++q) hs[c * 36 + q] += M[q];
    }
    __syncthreads();
    if (sub == 3) {
#pragma unroll
        for (int q = 0; q < 36; ++q) hs[c * 36 + q] += M[q];
    }
    __syncthreads();
    float4* dst = (float4*)(Mpart + ((size_t)n * SPL + s) * 2304);
    const float4* src = (const float4*)hs;
    for (int idx = threadIdx.x; idx < 576; idx += 256) dst[idx] = src[idx];
}

// ---------- coeff_k: reduce 32 partials, routing math, emit coef[8] ----------
__global__ __launch_bounds__(64) void coeff_k(const float* __restrict__ Mpart,
                                              float* __restrict__ coefb) {
    int n = blockIdx.x;
    int c = threadIdx.x;
    float M[36];
#pragma unroll
    for (int q = 0; q < 36; ++q) M[q] = 0.f;
    for (int s2 = 0; s2 < SPL; ++s2) {
        const float* mp = Mpart + ((size_t)n * SPL + s2) * 2304 + c * 36;
#pragma unroll
        for (int q = 0; q < 9; ++q) {
            float4 v = *(const float4*)(mp + 4 * q);
            M[4 * q] += v.x; M[4 * q + 1] += v.y; M[4 * q + 2] += v.z; M[4 * q + 3] += v.w;
        }
    }
    float rs[8];
#pragma unroll
    for (int i = 0; i < 8; ++i) rs[i] = 0.f;
    {
        int idx2 = 0;
#pragma unroll
        for (int i = 0; i < 8; ++i)
#pragma unroll
            for (int j = i; j < 8; ++j, ++idx2) {
                rs[i] += M[idx2];
                if (j > i) rs[j] += M[idx2];
            }
    }
    float sumAll = 0.f;
#pragma unroll
    for (int i = 0; i < 8; ++i) sumAll += rs[i];
    float sqn1 = sumAll * (1.f / 64.f);
    float binv = 1.f / (8.f * (1.f + sqn1));
    float bv[8], mx = -1e30f;
#pragma unroll
    for (int i = 0; i < 8; ++i) { bv[i] = rs[i] * binv; mx = fmaxf(mx, bv[i]); }
    float e[8], se = 0.f;
#pragma unroll
    for (int i = 0; i < 8; ++i) { e[i] = expf(bv[i] - mx); se += e[i]; }
    float sinv = 1.f / se;
    float ci_[8];
#pragma unroll
    for (int i = 0; i < 8; ++i) ci_[i] = e[i] * sinv;
    float sqn2 = 0.f;
    {
        int idx2 = 0;
#pragma unroll
        for (int i = 0; i < 8; ++i)
#pragma unroll
            for (int j = i; j < 8; ++j, ++idx2)
                sqn2 += ((j > i) ? 2.f : 1.f) * ci_[i] * ci_[j] * M[idx2];
    }
    float scale = 1.f / (1.f + sqn2);
#pragma unroll
    for (int i = 0; i < 8; ++i) coefb[((size_t)n * 64 + c) * 8 + i] = ci_[i] * scale;
}

// -------- out_k: one (n, l-tile) per block; LDS-staged; coalesced stores ------
__global__ __launch_bounds__(256) void out_k(const float* __restrict__ h2,
                                             const float* __restrict__ sq,
                                             const float* __restrict__ wA,
                                             const float* __restrict__ bA,
                                             const float* __restrict__ coefb,
                                             float* __restrict__ out) {
    __shared__ __align__(16) float hs[64 * 36];
    __shared__ __align__(16) float vout[64 * 33];   // +1 pad: conflict-free writes
    int n = blockIdx.x / NTT;
    int t = blockIdx.x - n * NTT;
    int l0 = t * 32;
    int c = threadIdx.x & 63;
    int sub = threadIdx.x >> 6;
    int lsub = sub * 8;
    int srow = threadIdx.x >> 2;
    int sph = threadIdx.x & 3;
    float inv = 1.f / (1.f + sq[n * 64 + srow]);
    float wreg[24];
#pragma unroll
    for (int q = 0; q < 24; ++q) wreg[q] = wA[c * 24 + q];
    float biasc = bA[c];
    float coef[8];
#pragma unroll
    for (int i = 0; i < 8; ++i) coef[i] = coefb[((size_t)n * 64 + c) * 8 + i];
    const float* h2r = h2 + ((size_t)n * 64 + srow) * L_LEN;
#pragma unroll
    for (int k = 0; k < 9; ++k) {
        int j = sph + 4 * k;
        int l = l0 + j - 1;
        hs[srow * 36 + j] = (l >= 0 && l < L_LEN) ? h2r[l] * inv : 0.f;
    }
    __syncthreads();
    int lbase = l0 + lsub;
    if (lbase < L_LEN) {
        float v[8];
#pragma unroll
        for (int m = 0; m < 8; ++m) v[m] = 0.f;
#pragma unroll
        for (int i = 0; i < 8; ++i) {
            float Hi[8];
#pragma unroll
            for (int m = 0; m < 8; ++m) Hi[m] = biasc;
#pragma unroll
            for (int p = 0; p < 8; ++p) {
                const float* r = &hs[(8 * i + p) * 36 + lsub];
                float4 ra = *(const float4*)r;
                float4 rb = *(const float4*)(r + 4);
                float2 rc = *(const float2*)(r + 8);
                float rr[10] = {ra.x, ra.y, ra.z, ra.w, rb.x, rb.y, rb.z, rb.w, rc.x, rc.y};
                float w0 = wreg[p * 3], w1 = wreg[p * 3 + 1], w2v = wreg[p * 3 + 2];
#pragma unroll
                for (int m = 0; m < 8; ++m)
                    Hi[m] += w0 * rr[m] + w1 * rr[m + 1] + w2v * rr[m + 2];
            }
            float cw = coef[i];
#pragma unroll
            for (int m = 0; m < 8; ++m) v[m] += cw * Hi[m];
        }
#pragma unroll
        for (int m = 0; m < 8; ++m) vout[c * 33 + lsub + m] = v[m];
    }
    __syncthreads();
    // 64 rows x 8 float4; 4500 % 4 == 0 so per-float4 guard is exact
#pragma unroll
    for (int it = 0; it < 2; ++it) {
        int fidx = threadIdx.x + it * 256;
        int cc = fidx >> 3;
        int qq = fidx & 7;
        int l = l0 + qq * 4;
        if (l < L_LEN)
            *(float4*)(out + ((size_t)n * 64 + cc) * L_LEN + l) =
                *(const float4*)&vout[cc * 33 + qq * 4];
    }
}

extern "C" void kernel_launch(void* const* d_in, const int* in_sizes, int n_in,
                              void* d_out, int out_size, void* d_ws, size_t ws_size,
                              hipStream_t stream) {
    const float* x  = (const float*)d_in[0];
    const float* w1 = (const float*)d_in[1];
    const float* w2 = (const float*)d_in[2];
    const float* wA = (const float*)d_in[3];
    const float* bA = (const float*)d_in[4];
    float* out = (float*)d_out;
    char* ws = (char*)d_ws;
    const size_t HB = (size_t)64 * 64 * L_LEN * 4;   // 73,728,000 B
    float* h1    = (float*)ws;                        // dead after conv2
    float* h2    = (float*)(ws + HB);
    float* sq    = (float*)(ws + 2 * HB);             // 16 KB
    float* w2t   = (float*)(ws + 2 * HB + 16384);     // 80 KB
    float* Mpart = h1;                                // overlay: 64*32*2304*4 = 18.9 MB
    float* coefb = (float*)(ws + 24 * 1024 * 1024);   // overlay in h1 past Mpart

    hipMemsetAsync(sq, 0, 64 * 64 * sizeof(float), stream);
    prep_w2t_k<<<80, 256, 0, stream>>>(w2, w2t);
    conv1_k<<<4096, 256, 0, stream>>>(x, w1, h1);
    conv2_k<<<64 * NT2, 256, 0, stream>>>(h1, w2t, h2, sq);
    gram_k<<<64 * SPL, 256, 0, stream>>>(h2, sq, wA, bA, Mpart);
    coeff_k<<<64, 64, 0, stream>>>(Mpart, coefb);
    out_k<<<64 * NTT, 256, 0, stream>>>(h2, sq, wA, bA, coefb, out);
}

// Round 7
// 757.676 us; speedup vs baseline: 2.2948x; 1.1950x over previous
//
#include <hip/hip_runtime.h>
#include <math.h>

#define L_LEN 4500
#define T2 128
#define NT2 36    // ceil(4500/128)
#define KSPL 12   // K-splits for corr_k
#define NT64 71   // ceil(4500/64)

// ---------------- prep: transpose conv2 weights to [cin][g][k] ----------------
__global__ void prep_w2t_k(const float* __restrict__ w2, float* __restrict__ w2t) {
    int i = blockIdx.x * 256 + threadIdx.x;
    if (i < 64 * 64 * 5) {
        int k = i / 320;
        int r = i - k * 320;
        int c = r / 5;
        int g = r - c * 5;
        w2t[(c * 5 + g) * 64 + k] = w2[i];
    }
}

// ---------------- conv1: x (64,1,L) -> h1 (64,64,L), k=7, SAME ----------------
__global__ __launch_bounds__(256) void conv1_k(const float* __restrict__ x,
                                               const float* __restrict__ w1,
                                               float* __restrict__ h1) {
    int n = blockIdx.x >> 6, k = blockIdx.x & 63;
    float w[7];
#pragma unroll
    for (int g = 0; g < 7; ++g) w[g] = w1[k * 7 + g];
    const float* xr = x + (size_t)n * L_LEN;
    float* hr = h1 + ((size_t)n * 64 + k) * L_LEN;
    for (int l = threadIdx.x; l < L_LEN; l += 256) {
        float a = 0.f;
#pragma unroll
        for (int g = 0; g < 7; ++g) {
            int p = l + g - 3;
            if (p >= 0 && p < L_LEN) a += w[g] * xr[p];
        }
        hr[l] = a;
    }
}

// -- conv2: h1 -> h2 (raw), k=5, SAME; + sumsq and rowsum atomics per (n,k) ---
__global__ __launch_bounds__(256) void conv2_k(const float* __restrict__ h1,
                                               const float* __restrict__ w2t,
                                               float* __restrict__ h2,
                                               float* __restrict__ sq,
                                               float* __restrict__ rowsum) {
    __shared__ float h1s[64][T2 + 4];
    __shared__ float sqred[4][64];
    __shared__ float rsred[4][64];
    int n = blockIdx.x / NT2;
    int t = blockIdx.x - n * NT2;
    int l0 = t * T2;
    const float* h1n = h1 + (size_t)n * 64 * L_LEN;
    for (int idx = threadIdx.x; idx < 64 * (T2 + 4); idx += 256) {
        int ci = idx / (T2 + 4);
        int j = idx - ci * (T2 + 4);
        int l = l0 + j - 2;
        h1s[ci][j] = (l >= 0 && l < L_LEN) ? h1n[(size_t)ci * L_LEN + l] : 0.f;
    }
    __syncthreads();
    int k = threadIdx.x & 63;
    int lg = threadIdx.x >> 6;
    int base = lg * 32;
    float acc[32];
#pragma unroll
    for (int m = 0; m < 32; ++m) acc[m] = 0.f;
    for (int ci = 0; ci < 64; ++ci) {
        const float* wr = w2t + ci * 320 + k;
        float w0 = wr[0], w1 = wr[64], w2v = wr[128], w3 = wr[192], w4 = wr[256];
        float v[36];
#pragma unroll
        for (int j = 0; j < 36; ++j) v[j] = h1s[ci][base + j];
#pragma unroll
        for (int m = 0; m < 32; ++m)
            acc[m] += w0 * v[m] + w1 * v[m + 1] + w2v * v[m + 2] + w3 * v[m + 3] + w4 * v[m + 4];
    }
    float s = 0.f, r2 = 0.f;
    float* h2r = h2 + ((size_t)n * 64 + k) * L_LEN;
#pragma unroll
    for (int m = 0; m < 32; ++m) {
        int l = l0 + base + m;
        if (l < L_LEN) { h2r[l] = acc[m]; s += acc[m] * acc[m]; r2 += acc[m]; }
    }
    sqred[lg][k] = s;
    rsred[lg][k] = r2;
    __syncthreads();
    if (threadIdx.x < 64) {
        float tot = sqred[0][threadIdx.x] + sqred[1][threadIdx.x] +
                    sqred[2][threadIdx.x] + sqred[3][threadIdx.x];
        atomicAdd(&sq[n * 64 + threadIdx.x], tot);
        float rt = rsred[0][threadIdx.x] + rsred[1][threadIdx.x] +
                   rsred[2][threadIdx.x] + rsred[3][threadIdx.x];
        atomicAdd(&rowsum[n * 64 + threadIdx.x], rt);
    }
}

// ---- corr_k: R[a][b][d] = sum_l h2[a][l] * h2[b][l+d-2]  (raw h2, OOB=0) ----
// Transposed LDS tile: hsT[j][a], j = l - l0 + 4. Each ds_read_b128 fetches
// 4 a-rows (the float4 components) -> 64 distinct floats/instr, conflict-free.
// thread (ta,tb) owns a=4ta..+3, b=4tb..+3, all 5 lags: acc[4][4][5].
__global__ __launch_bounds__(256) void corr_k(const float* __restrict__ h2,
                                              float* __restrict__ Rp) {
    __shared__ __align__(16) float hsT[72 * 68];
    int n = blockIdx.x / KSPL;
    int s = blockIdx.x - n * KSPL;
    int ta = threadIdx.x & 15;
    int tb = threadIdx.x >> 4;
    const float* h2n = h2 + (size_t)n * 64 * L_LEN;
    float acc[4][4][5];
#pragma unroll
    for (int ar = 0; ar < 4; ++ar)
#pragma unroll
        for (int br = 0; br < 4; ++br)
#pragma unroll
            for (int d = 0; d < 5; ++d) acc[ar][br][d] = 0.f;
    int as = threadIdx.x >> 6;
    int jl = threadIdx.x & 63;
    int j2 = 64 + (threadIdx.x & 7);
    int a2 = threadIdx.x >> 3;   // 0..31

    for (int t = s; t < NT64; t += KSPL) {
        int l0 = t * 64;
        __syncthreads();
        {
            int l = l0 + jl - 4;
            bool ok = (l >= 0 && l < L_LEN);
#pragma unroll
            for (int ait = 0; ait < 16; ++ait) {
                int a = as * 16 + ait;
                hsT[jl * 68 + a] = ok ? h2n[(size_t)a * L_LEN + l] : 0.f;
            }
        }
        {
            int l = l0 + j2 - 4;
            bool ok = (l >= 0 && l < L_LEN);
            hsT[j2 * 68 + a2] = ok ? h2n[(size_t)a2 * L_LEN + l] : 0.f;
            hsT[j2 * 68 + a2 + 32] = ok ? h2n[(size_t)(a2 + 32) * L_LEN + l] : 0.f;
        }
        __syncthreads();
        for (int lk = 0; lk < 16; ++lk) {
            float aw[4][4], bw[8][4];
#pragma unroll
            for (int m = 0; m < 4; ++m) {
                float4 v = *(const float4*)&hsT[(lk * 4 + 4 + m) * 68 + ta * 4];
                aw[m][0] = v.x; aw[m][1] = v.y; aw[m][2] = v.z; aw[m][3] = v.w;
            }
#pragma unroll
            for (int q = 0; q < 8; ++q) {
                float4 v = *(const float4*)&hsT[(lk * 4 + 2 + q) * 68 + tb * 4];
                bw[q][0] = v.x; bw[q][1] = v.y; bw[q][2] = v.z; bw[q][3] = v.w;
            }
#pragma unroll
            for (int m = 0; m < 4; ++m)
#pragma unroll
                for (int d = 0; d < 5; ++d)
#pragma unroll
                    for (int ar = 0; ar < 4; ++ar)
#pragma unroll
                        for (int br = 0; br < 4; ++br)
                            acc[ar][br][d] += aw[m][ar] * bw[m + d][br];
        }
    }
    // pack & write, fully coalesced: Rp[(n*KSPL+s)][q4*1024 + tid*4 + e]
    float* base = Rp + (size_t)(n * KSPL + s) * 20480 + threadIdx.x * 4;
    float tmp[4];
#pragma unroll
    for (int k = 0; k < 80; ++k) {
        int ar = k / 20;
        int rem = k - 20 * ar;
        int br = rem / 5;
        int d = rem - 5 * br;
        tmp[k & 3] = acc[ar][br][d];
        if ((k & 3) == 3) {
            float4 w4 = {tmp[0], tmp[1], tmp[2], tmp[3]};
            *(float4*)(base + (k >> 2) * 1024) = w4;
        }
    }
}

// ---------- reduce_k: element-wise sum of the KSPL partials (layout-agnostic) -
__global__ __launch_bounds__(256) void reduce_k(const float* __restrict__ Rp,
                                                float* __restrict__ Rsum) {
    int n = blockIdx.x / 80;
    int bb = blockIdx.x - n * 80;
    int idx = bb * 256 + threadIdx.x;
    float s = 0.f;
#pragma unroll
    for (int s2 = 0; s2 < KSPL; ++s2) s += Rp[((size_t)n * KSPL + s2) * 20480 + idx];
    Rsum[(size_t)n * 20480 + idx] = s;
}

// ---- mcoef_k: assemble M[c][36] from R + bias/edge terms, then routing ------
__global__ __launch_bounds__(256) void mcoef_k(const float* __restrict__ Rsum,
                                               const float* __restrict__ h2,
                                               const float* __restrict__ sq,
                                               const float* __restrict__ rowsum,
                                               const float* __restrict__ wA,
                                               const float* __restrict__ bA,
                                               float* __restrict__ coefb) {
    __shared__ float Rsub[320];
    __shared__ float Mred[64 * 36];
    __shared__ float s0s[64], s1s[64], Ts[64], invs[64];
    int n = blockIdx.x;
    int c = threadIdx.x & 63;
    int sub = threadIdx.x >> 6;
    if (threadIdx.x < 64) {
        int a = threadIdx.x;
        s0s[a] = h2[((size_t)n * 64 + a) * L_LEN + 0];
        s1s[a] = h2[((size_t)n * 64 + a) * L_LEN + (L_LEN - 1)];
        Ts[a]  = rowsum[n * 64 + a];
        invs[a] = 1.f / (1.f + sq[n * 64 + a]);
    }
    float wreg[24];
#pragma unroll
    for (int q = 0; q < 24; ++q) wreg[q] = wA[c * 24 + q];
    float bc = bA[c];
    __syncthreads();
    // SG[i] = sum_l conv-part of H_i (for bias cross terms)
    float SG[8];
#pragma unroll
    for (int i = 0; i < 8; ++i) {
        float s = 0.f;
#pragma unroll
        for (int p = 0; p < 8; ++p) {
            int a = 8 * i + p;
            float Ta = Ts[a];
            s += invs[a] * (wreg[p * 3 + 0] * (Ta - s1s[a]) +
                            wreg[p * 3 + 1] * Ta +
                            wreg[p * 3 + 2] * (Ta - s0s[a]));
        }
        SG[i] = s;
    }
    float M36[36];
    int ij = 0;
#pragma unroll
    for (int i = 0; i < 8; ++i) {
#pragma unroll
        for (int j = i; j < 8; ++j) {
            __syncthreads();
            for (int fidx = threadIdx.x; fidx < 320; fidx += 256) {
                int p = fidx / 40;
                int r = fidx - 40 * p;
                int pp = r / 5;
                int d = r - 5 * pp;
                int a = 8 * i + p, b = 8 * j + pp;
                int tth = (a >> 2) + ((b >> 2) << 4);
                int flat = (((a & 3) << 2) + (b & 3)) * 5 + d;
                Rsub[fidx] = Rsum[(size_t)n * 20480 + (flat >> 2) * 1024 + tth * 4 + (flat & 3)];
            }
            __syncthreads();
            float acc = 0.f;
#pragma unroll
            for (int pl = 0; pl < 2; ++pl) {
                int p = sub * 2 + pl;
                int a = 8 * i + p;
                float ia = invs[a];
                float w0 = wreg[p * 3], w1 = wreg[p * 3 + 1], w2v = wreg[p * 3 + 2];
                float e1a = s1s[a], e0a = s0s[a];
#pragma unroll
                for (int pp = 0; pp < 8; ++pp) {
                    int b = 8 * j + pp;
                    float q0 = wreg[pp * 3], q1 = wreg[pp * 3 + 1], q2 = wreg[pp * 3 + 2];
                    const float* R5 = &Rsub[(p * 8 + pp) * 5];
                    float term = (w2v * q0) * R5[0]
                               + (w1 * q0 + w2v * q1) * R5[1]
                               + (w0 * q0 + w1 * q1 + w2v * q2) * R5[2]
                               + (w0 * q1 + w1 * q2) * R5[3]
                               + (w0 * q2) * R5[4]
                               - (w0 * q0) * (e1a * s1s[b])
                               - (w2v * q2) * (e0a * s0s[b]);
                    acc += ia * invs[b] * term;
                }
            }
            M36[ij] = acc;
            ++ij;
        }
    }
    __syncthreads();
    if (sub == 0) {
#pragma unroll
        for (int q = 0; q < 36; ++q) Mred[c * 36 + q] = M36[q];
    }
    __syncthreads();
    if (sub == 1) {
#pragma unroll
        for (int q = 0; q < 36; ++q) Mred[c * 36 + q] += M36[q];
    }
    __syncthreads();
    if (sub == 2) {
#pragma unroll
        for (int q = 0; q < 36; ++q) Mred[c * 36 + q] += M36[q];
    }
    __syncthreads();
    if (sub == 3) {
#pragma unroll
        for (int q = 0; q < 36; ++q) Mred[c * 36 + q] += M36[q];
    }
    __syncthreads();
    if (threadIdx.x < 64) {
        float M[36];
        {
            int k2 = 0;
#pragma unroll
            for (int i = 0; i < 8; ++i)
#pragma unroll
                for (int j = i; j < 8; ++j, ++k2)
                    M[k2] = Mred[c * 36 + k2] + bc * (SG[i] + SG[j]) + 4500.f * bc * bc;
        }
        float rs[8];
#pragma unroll
        for (int i = 0; i < 8; ++i) rs[i] = 0.f;
        {
            int idx2 = 0;
#pragma unroll
            for (int i = 0; i < 8; ++i)
#pragma unroll
                for (int j = i; j < 8; ++j, ++idx2) {
                    rs[i] += M[idx2];
                    if (j > i) rs[j] += M[idx2];
                }
        }
        float sumAll = 0.f;
#pragma unroll
        for (int i = 0; i < 8; ++i) sumAll += rs[i];
        float sqn1 = sumAll * (1.f / 64.f);
        float binv = 1.f / (8.f * (1.f + sqn1));
        float bv[8], mx = -1e30f;
#pragma unroll
        for (int i = 0; i < 8; ++i) { bv[i] = rs[i] * binv; mx = fmaxf(mx, bv[i]); }
        float e[8], se = 0.f;
#pragma unroll
        for (int i = 0; i < 8; ++i) { e[i] = expf(bv[i] - mx); se += e[i]; }
        float sinv = 1.f / se;
        float ci_[8];
#pragma unroll
        for (int i = 0; i < 8; ++i) ci_[i] = e[i] * sinv;
        float sqn2 = 0.f;
        {
            int idx2 = 0;
#pragma unroll
            for (int i = 0; i < 8; ++i)
#pragma unroll
                for (int j = i; j < 8; ++j, ++idx2)
                    sqn2 += ((j > i) ? 2.f : 1.f) * ci_[i] * ci_[j] * M[idx2];
        }
        float scale = 1.f / (1.f + sqn2);
#pragma unroll
        for (int i = 0; i < 8; ++i) coefb[((size_t)n * 64 + c) * 8 + i] = ci_[i] * scale;
    }
}

// -------- weff_k: WeffT[n][a][g][c] = coef[n,c,a>>3]*W[c,a&7,g]*inv[n,a] ------
__global__ __launch_bounds__(256) void weff_k(const float* __restrict__ coefb,
                                              const float* __restrict__ wA,
                                              const float* __restrict__ sq,
                                              const float* __restrict__ bA,
                                              float* __restrict__ WeffT,
                                              float* __restrict__ vbias) {
    int n = blockIdx.x;
    for (int idx = threadIdx.x; idx < 12288; idx += 256) {
        int a = idx / 192;
        int r = idx - 192 * a;
        int g = r >> 6;
        int c = r & 63;
        float inv = 1.f / (1.f + sq[n * 64 + a]);
        WeffT[(size_t)n * 12288 + idx] =
            coefb[((size_t)n * 64 + c) * 8 + (a >> 3)] * wA[c * 24 + (a & 7) * 3 + g] * inv;
    }
    if (threadIdx.x < 64) {
        float s = 0.f;
#pragma unroll
        for (int i = 0; i < 8; ++i) s += coefb[((size_t)n * 64 + threadIdx.x) * 8 + i];
        vbias[n * 64 + threadIdx.x] = bA[threadIdx.x] * s;
    }
}

// -------- outconv_k: out = Weff (64->64, k=3) * h2 + vbias (conv2 clone) -----
__global__ __launch_bounds__(256) void outconv_k(const float* __restrict__ h2,
                                                 const float* __restrict__ WeffT,
                                                 const float* __restrict__ vbias,
                                                 float* __restrict__ out) {
    __shared__ float hs[64][T2 + 2];
    int n = blockIdx.x / NT2;
    int t = blockIdx.x - n * NT2;
    int l0 = t * T2;
    const float* h2n = h2 + (size_t)n * 64 * L_LEN;
    for (int idx = threadIdx.x; idx < 64 * (T2 + 2); idx += 256) {
        int ci = idx / (T2 + 2);
        int j = idx - ci * (T2 + 2);
        int l = l0 + j - 1;
        hs[ci][j] = (l >= 0 && l < L_LEN) ? h2n[(size_t)ci * L_LEN + l] : 0.f;
    }
    __syncthreads();
    int k = threadIdx.x & 63;
    int lg = threadIdx.x >> 6;
    int base = lg * 32;
    float acc[32];
#pragma unroll
    for (int m = 0; m < 32; ++m) acc[m] = 0.f;
    const float* wp = WeffT + (size_t)n * 12288 + k;
    for (int ci = 0; ci < 64; ++ci) {
        float w0 = wp[ci * 192], w1 = wp[ci * 192 + 64], w2v = wp[ci * 192 + 128];
        float v[34];
#pragma unroll
        for (int j = 0; j < 34; ++j) v[j] = hs[ci][base + j];
#pragma unroll
        for (int m = 0; m < 32; ++m)
            acc[m] += w0 * v[m] + w1 * v[m + 1] + w2v * v[m + 2];
    }
    float vb = vbias[n * 64 + k];
    float* outr = out + ((size_t)n * 64 + k) * L_LEN;
#pragma unroll
    for (int m = 0; m < 32; ++m) {
        int l = l0 + base + m;
        if (l < L_LEN) outr[l] = acc[m] + vb;
    }
}

extern "C" void kernel_launch(void* const* d_in, const int* in_sizes, int n_in,
                              void* d_out, int out_size, void* d_ws, size_t ws_size,
                              hipStream_t stream) {
    const float* x  = (const float*)d_in[0];
    const float* w1 = (const float*)d_in[1];
    const float* w2 = (const float*)d_in[2];
    const float* wA = (const float*)d_in[3];
    const float* bA = (const float*)d_in[4];
    float* out = (float*)d_out;
    char* ws = (char*)d_ws;
    const size_t HB = (size_t)64 * 64 * L_LEN * 4;   // 73,728,000 B
    float* h1     = (float*)ws;                       // dead after conv2 -> overlay
    float* h2     = (float*)(ws + HB);
    float* sq     = (float*)(ws + 2 * HB);            // 16 KB
    float* rowsum = (float*)(ws + 2 * HB + 16384);    // 16 KB
    float* w2t    = (float*)(ws + 2 * HB + 32768);    // 80 KB
    // overlays inside h1 (all written after conv2):
    float* Rp    = h1;                                       // 62,914,560 B
    float* Rsum  = (float*)(ws + 62914560);                  //  5,242,880 B
    float* coefb = (float*)(ws + 68157440);                  //    131,072 B
    float* WeffT = (float*)(ws + 68288512);                  //  3,145,728 B
    float* vbias = (float*)(ws + 71434240);                  //     16,384 B

    hipMemsetAsync(sq, 0, 2 * 64 * 64 * sizeof(float), stream);  // sq + rowsum
    prep_w2t_k<<<80, 256, 0, stream>>>(w2, w2t);
    conv1_k<<<4096, 256, 0, stream>>>(x, w1, h1);
    conv2_k<<<64 * NT2, 256, 0, stream>>>(h1, w2t, h2, sq, rowsum);
    corr_k<<<64 * KSPL, 256, 0, stream>>>(h2, Rp);
    reduce_k<<<64 * 80, 256, 0, stream>>>(Rp, Rsum);
    mcoef_k<<<64, 256, 0, stream>>>(Rsum, h2, sq, rowsum, wA, bA, coefb);
    weff_k<<<64, 256, 0, stream>>>(coefb, wA, sq, bA, WeffT, vbias);
    outconv_k<<<64 * NT2, 256, 0, stream>>>(h2, WeffT, vbias, out);
}

// Round 8
// 596.315 us; speedup vs baseline: 2.9158x; 1.2706x over previous
//
#include <hip/hip_runtime.h>
#include <math.h>

#define L_LEN 4500
#define T2 128
#define NT2 36    // ceil(4500/128)
#define KSPL 12   // K-splits for corr_k
#define NT64 71   // ceil(4500/64)

// ---------------- prep: transpose conv2 weights to [cin][g][k] ----------------
__global__ void prep_w2t_k(const float* __restrict__ w2, float* __restrict__ w2t) {
    int i = blockIdx.x * 256 + threadIdx.x;
    if (i < 64 * 64 * 5) {
        int k = i / 320;
        int r = i - k * 320;
        int c = r / 5;
        int g = r - c * 5;
        w2t[(c * 5 + g) * 64 + k] = w2[i];
    }
}

// ---- conv12_k: fused conv1 (k=7) + conv2 (k=5) : x -> h2, no h1 round-trip ---
// Phase A: stage x window. Phase B: h1 tile in LDS (64 x 132).
// Phase C: register-tiled GEMM, thread = 4k x 8l; LDS reads are distinct-address
// ds_read_b128 (full LDS BW), weights are coalesced float4 from L2-resident w2t.
__global__ __launch_bounds__(256) void conv12_k(const float* __restrict__ x,
                                                const float* __restrict__ w1,
                                                const float* __restrict__ w2t,
                                                float* __restrict__ h2) {
    __shared__ float xs[144];
    __shared__ __align__(16) float h1s[64 * 132];
    int n = blockIdx.x / NT2;
    int t = blockIdx.x - n * NT2;
    int l0 = t * T2;
    const float* xr = x + (size_t)n * L_LEN;
    if (threadIdx.x < 138) {
        int l = l0 - 5 + threadIdx.x;
        xs[threadIdx.x] = (l >= 0 && l < L_LEN) ? xr[l] : 0.f;
    }
    __syncthreads();
    {
        int vci = threadIdx.x >> 2;
        int seg = threadIdx.x & 3;
        int j0 = seg * 33;
        float w[7];
#pragma unroll
        for (int g = 0; g < 7; ++g) w[g] = w1[vci * 7 + g];
        for (int jj = 0; jj < 33; ++jj) {
            int j = j0 + jj;
            int l = l0 - 2 + j;
            float a = 0.f;
#pragma unroll
            for (int g = 0; g < 7; ++g) a += w[g] * xs[j + g];
            h1s[vci * 132 + j] = (l >= 0 && l < L_LEN) ? a : 0.f;   // SAME-pad zeroing
        }
    }
    __syncthreads();
    int ta = threadIdx.x & 15;
    int tb = threadIdx.x >> 4;
    int k0 = ta * 4;
    int lt = tb * 8;
    float acc[4][8];
#pragma unroll
    for (int kq = 0; kq < 4; ++kq)
#pragma unroll
        for (int m = 0; m < 8; ++m) acc[kq][m] = 0.f;
    for (int ci = 0; ci < 64; ++ci) {
        const float* hrow = &h1s[ci * 132 + lt];
        float4 wa = *(const float4*)hrow;
        float4 wb = *(const float4*)(hrow + 4);
        float4 wc = *(const float4*)(hrow + 8);
        float win[12] = {wa.x, wa.y, wa.z, wa.w, wb.x, wb.y, wb.z, wb.w,
                         wc.x, wc.y, wc.z, wc.w};
        const float* wp = w2t + ci * 320 + k0;
#pragma unroll
        for (int g = 0; g < 5; ++g) {
            float4 wv = *(const float4*)(wp + g * 64);
#pragma unroll
            for (int m = 0; m < 8; ++m) {
                acc[0][m] += wv.x * win[m + g];
                acc[1][m] += wv.y * win[m + g];
                acc[2][m] += wv.z * win[m + g];
                acc[3][m] += wv.w * win[m + g];
            }
        }
    }
    int lbase = l0 + lt;
#pragma unroll
    for (int kq = 0; kq < 4; ++kq) {
        float* orow = h2 + ((size_t)n * 64 + k0 + kq) * L_LEN + lbase;
        if (lbase < L_LEN) {
            float4 s0 = {acc[kq][0], acc[kq][1], acc[kq][2], acc[kq][3]};
            *(float4*)orow = s0;
        }
        if (lbase + 4 < L_LEN) {
            float4 s1 = {acc[kq][4], acc[kq][5], acc[kq][6], acc[kq][7]};
            *(float4*)(orow + 4) = s1;
        }
    }
}

// ---------- sumstat_k: per (n,k) row -> sq (sum of squares), rowsum ----------
__global__ __launch_bounds__(256) void sumstat_k(const float* __restrict__ h2,
                                                 float* __restrict__ sq,
                                                 float* __restrict__ rowsum) {
    int nk = blockIdx.x;
    const float4* row = (const float4*)(h2 + (size_t)nk * L_LEN);
    float s = 0.f, r = 0.f;
    for (int i = threadIdx.x; i < L_LEN / 4; i += 256) {
        float4 v = row[i];
        s += v.x * v.x + v.y * v.y + v.z * v.z + v.w * v.w;
        r += v.x + v.y + v.z + v.w;
    }
#pragma unroll
    for (int off = 32; off; off >>= 1) {
        s += __shfl_down(s, off);
        r += __shfl_down(r, off);
    }
    __shared__ float ss[4], rr[4];
    if ((threadIdx.x & 63) == 0) { ss[threadIdx.x >> 6] = s; rr[threadIdx.x >> 6] = r; }
    __syncthreads();
    if (threadIdx.x == 0) {
        sq[nk] = ss[0] + ss[1] + ss[2] + ss[3];
        rowsum[nk] = rr[0] + rr[1] + rr[2] + rr[3];
    }
}

// ---- corr_k: R[a][b][d] = sum_l h2[a][l] * h2[b][l+d-2]  (raw h2, OOB=0) ----
__global__ __launch_bounds__(256) void corr_k(const float* __restrict__ h2,
                                              float* __restrict__ Rp) {
    __shared__ __align__(16) float hsT[72 * 68];
    int n = blockIdx.x / KSPL;
    int s = blockIdx.x - n * KSPL;
    int ta = threadIdx.x & 15;
    int tb = threadIdx.x >> 4;
    const float* h2n = h2 + (size_t)n * 64 * L_LEN;
    float acc[4][4][5];
#pragma unroll
    for (int ar = 0; ar < 4; ++ar)
#pragma unroll
        for (int br = 0; br < 4; ++br)
#pragma unroll
            for (int d = 0; d < 5; ++d) acc[ar][br][d] = 0.f;
    int as = threadIdx.x >> 6;
    int jl = threadIdx.x & 63;
    int j2 = 64 + (threadIdx.x & 7);
    int a2 = threadIdx.x >> 3;   // 0..31

    for (int t = s; t < NT64; t += KSPL) {
        int l0 = t * 64;
        __syncthreads();
        {
            int l = l0 + jl - 4;
            bool ok = (l >= 0 && l < L_LEN);
#pragma unroll
            for (int ait = 0; ait < 16; ++ait) {
                int a = as * 16 + ait;
                hsT[jl * 68 + a] = ok ? h2n[(size_t)a * L_LEN + l] : 0.f;
            }
        }
        {
            int l = l0 + j2 - 4;
            bool ok = (l >= 0 && l < L_LEN);
            hsT[j2 * 68 + a2] = ok ? h2n[(size_t)a2 * L_LEN + l] : 0.f;
            hsT[j2 * 68 + a2 + 32] = ok ? h2n[(size_t)(a2 + 32) * L_LEN + l] : 0.f;
        }
        __syncthreads();
        for (int lk = 0; lk < 16; ++lk) {
            float aw[4][4], bw[8][4];
#pragma unroll
            for (int m = 0; m < 4; ++m) {
                float4 v = *(const float4*)&hsT[(lk * 4 + 4 + m) * 68 + ta * 4];
                aw[m][0] = v.x; aw[m][1] = v.y; aw[m][2] = v.z; aw[m][3] = v.w;
            }
#pragma unroll
            for (int q = 0; q < 8; ++q) {
                float4 v = *(const float4*)&hsT[(lk * 4 + 2 + q) * 68 + tb * 4];
                bw[q][0] = v.x; bw[q][1] = v.y; bw[q][2] = v.z; bw[q][3] = v.w;
            }
#pragma unroll
            for (int m = 0; m < 4; ++m)
#pragma unroll
                for (int d = 0; d < 5; ++d)
#pragma unroll
                    for (int ar = 0; ar < 4; ++ar)
#pragma unroll
                        for (int br = 0; br < 4; ++br)
                            acc[ar][br][d] += aw[m][ar] * bw[m + d][br];
        }
    }
    float* base = Rp + (size_t)(n * KSPL + s) * 20480 + threadIdx.x * 4;
    float tmp[4];
#pragma unroll
    for (int k = 0; k < 80; ++k) {
        int ar = k / 20;
        int rem = k - 20 * ar;
        int br = rem / 5;
        int d = rem - 5 * br;
        tmp[k & 3] = acc[ar][br][d];
        if ((k & 3) == 3) {
            float4 w4 = {tmp[0], tmp[1], tmp[2], tmp[3]};
            *(float4*)(base + (k >> 2) * 1024) = w4;
        }
    }
}

// ---------- reduce_k: element-wise sum of the KSPL partials ------------------
__global__ __launch_bounds__(256) void reduce_k(const float* __restrict__ Rp,
                                                float* __restrict__ Rsum) {
    int n = blockIdx.x / 80;
    int bb = blockIdx.x - n * 80;
    int idx = bb * 256 + threadIdx.x;
    float s = 0.f;
#pragma unroll
    for (int s2 = 0; s2 < KSPL; ++s2) s += Rp[((size_t)n * KSPL + s2) * 20480 + idx];
    Rsum[(size_t)n * 20480 + idx] = s;
}

// ---- mcoef_k: assemble M[c][36] from R + bias/edge terms, then routing ------
__global__ __launch_bounds__(256) void mcoef_k(const float* __restrict__ Rsum,
                                               const float* __restrict__ h2,
                                               const float* __restrict__ sq,
                                               const float* __restrict__ rowsum,
                                               const float* __restrict__ wA,
                                               const float* __restrict__ bA,
                                               float* __restrict__ coefb) {
    __shared__ float Rsub[320];
    __shared__ float Mred[64 * 36];
    __shared__ float s0s[64], s1s[64], Ts[64], invs[64];
    int n = blockIdx.x;
    int c = threadIdx.x & 63;
    int sub = threadIdx.x >> 6;
    if (threadIdx.x < 64) {
        int a = threadIdx.x;
        s0s[a] = h2[((size_t)n * 64 + a) * L_LEN + 0];
        s1s[a] = h2[((size_t)n * 64 + a) * L_LEN + (L_LEN - 1)];
        Ts[a]  = rowsum[n * 64 + a];
        invs[a] = 1.f / (1.f + sq[n * 64 + a]);
    }
    float wreg[24];
#pragma unroll
    for (int q = 0; q < 24; ++q) wreg[q] = wA[c * 24 + q];
    float bc = bA[c];
    __syncthreads();
    float SG[8];
#pragma unroll
    for (int i = 0; i < 8; ++i) {
        float s = 0.f;
#pragma unroll
        for (int p = 0; p < 8; ++p) {
            int a = 8 * i + p;
            float Ta = Ts[a];
            s += invs[a] * (wreg[p * 3 + 0] * (Ta - s1s[a]) +
                            wreg[p * 3 + 1] * Ta +
                            wreg[p * 3 + 2] * (Ta - s0s[a]));
        }
        SG[i] = s;
    }
    float M36[36];
    int ij = 0;
#pragma unroll
    for (int i = 0; i < 8; ++i) {
#pragma unroll
        for (int j = i; j < 8; ++j) {
            __syncthreads();
            for (int fidx = threadIdx.x; fidx < 320; fidx += 256) {
                int p = fidx / 40;
                int r = fidx - 40 * p;
                int pp = r / 5;
                int d = r - 5 * pp;
                int a = 8 * i + p, b = 8 * j + pp;
                int tth = (a >> 2) + ((b >> 2) << 4);
                int flat = (((a & 3) << 2) + (b & 3)) * 5 + d;
                Rsub[fidx] = Rsum[(size_t)n * 20480 + (flat >> 2) * 1024 + tth * 4 + (flat & 3)];
            }
            __syncthreads();
            float acc = 0.f;
#pragma unroll
            for (int pl = 0; pl < 2; ++pl) {
                int p = sub * 2 + pl;
                int a = 8 * i + p;
                float ia = invs[a];
                float w0 = wreg[p * 3], w1 = wreg[p * 3 + 1], w2v = wreg[p * 3 + 2];
                float e1a = s1s[a], e0a = s0s[a];
#pragma unroll
                for (int pp = 0; pp < 8; ++pp) {
                    int b = 8 * j + pp;
                    float q0 = wreg[pp * 3], q1 = wreg[pp * 3 + 1], q2 = wreg[pp * 3 + 2];
                    const float* R5 = &Rsub[(p * 8 + pp) * 5];
                    float term = (w2v * q0) * R5[0]
                               + (w1 * q0 + w2v * q1) * R5[1]
                               + (w0 * q0 + w1 * q1 + w2v * q2) * R5[2]
                               + (w0 * q1 + w1 * q2) * R5[3]
                               + (w0 * q2) * R5[4]
                               - (w0 * q0) * (e1a * s1s[b])
                               - (w2v * q2) * (e0a * s0s[b]);
                    acc += ia * invs[b] * term;
                }
            }
            M36[ij] = acc;
            ++ij;
        }
    }
    __syncthreads();
    if (sub == 0) {
#pragma unroll
        for (int q = 0; q < 36; ++q) Mred[c * 36 + q] = M36[q];
    }
    __syncthreads();
    if (sub == 1) {
#pragma unroll
        for (int q = 0; q < 36; ++q) Mred[c * 36 + q] += M36[q];
    }
    __syncthreads();
    if (sub == 2) {
#pragma unroll
        for (int q = 0; q < 36; ++q) Mred[c * 36 + q] += M36[q];
    }
    __syncthreads();
    if (sub == 3) {
#pragma unroll
        for (int q = 0; q < 36; ++q) Mred[c * 36 + q] += M36[q];
    }
    __syncthreads();
    if (threadIdx.x < 64) {
        float M[36];
        {
            int k2 = 0;
#pragma unroll
            for (int i = 0; i < 8; ++i)
#pragma unroll
                for (int j = i; j < 8; ++j, ++k2)
                    M[k2] = Mred[c * 36 + k2] + bc * (SG[i] + SG[j]) + 4500.f * bc * bc;
        }
        float rs[8];
#pragma unroll
        for (int i = 0; i < 8; ++i) rs[i] = 0.f;
        {
            int idx2 = 0;
#pragma unroll
            for (int i = 0; i < 8; ++i)
#pragma unroll
                for (int j = i; j < 8; ++j, ++idx2) {
                    rs[i] += M[idx2];
                    if (j > i) rs[j] += M[idx2];
                }
        }
        float sumAll = 0.f;
#pragma unroll
        for (int i = 0; i < 8; ++i) sumAll += rs[i];
        float sqn1 = sumAll * (1.f / 64.f);
        float binv = 1.f / (8.f * (1.f + sqn1));
        float bv[8], mx = -1e30f;
#pragma unroll
        for (int i = 0; i < 8; ++i) { bv[i] = rs[i] * binv; mx = fmaxf(mx, bv[i]); }
        float e[8], se = 0.f;
#pragma unroll
        for (int i = 0; i < 8; ++i) { e[i] = expf(bv[i] - mx); se += e[i]; }
        float sinv = 1.f / se;
        float ci_[8];
#pragma unroll
        for (int i = 0; i < 8; ++i) ci_[i] = e[i] * sinv;
        float sqn2 = 0.f;
        {
            int idx2 = 0;
#pragma unroll
            for (int i = 0; i < 8; ++i)
#pragma unroll
                for (int j = i; j < 8; ++j, ++idx2)
                    sqn2 += ((j > i) ? 2.f : 1.f) * ci_[i] * ci_[j] * M[idx2];
        }
        float scale = 1.f / (1.f + sqn2);
#pragma unroll
        for (int i = 0; i < 8; ++i) coefb[((size_t)n * 64 + c) * 8 + i] = ci_[i] * scale;
    }
}

// -------- weff_k: WeffT[n][a][g][c] = coef[n,c,a>>3]*W[c,a&7,g]*inv[n,a] ------
__global__ __launch_bounds__(256) void weff_k(const float* __restrict__ coefb,
                                              const float* __restrict__ wA,
                                              const float* __restrict__ sq,
                                              const float* __restrict__ bA,
                                              float* __restrict__ WeffT,
                                              float* __restrict__ vbias) {
    int n = blockIdx.x;
    for (int idx = threadIdx.x; idx < 12288; idx += 256) {
        int a = idx / 192;
        int r = idx - 192 * a;
        int g = r >> 6;
        int c = r & 63;
        float inv = 1.f / (1.f + sq[n * 64 + a]);
        WeffT[(size_t)n * 12288 + idx] =
            coefb[((size_t)n * 64 + c) * 8 + (a >> 3)] * wA[c * 24 + (a & 7) * 3 + g] * inv;
    }
    if (threadIdx.x < 64) {
        float s = 0.f;
#pragma unroll
        for (int i = 0; i < 8; ++i) s += coefb[((size_t)n * 64 + threadIdx.x) * 8 + i];
        vbias[n * 64 + threadIdx.x] = bA[threadIdx.x] * s;
    }
}

// ---- outconv_k: out = Weff (64->64, k=3) * h2 + vbias, register-tiled GEMM ---
__global__ __launch_bounds__(256) void outconv_k(const float* __restrict__ h2,
                                                 const float* __restrict__ WeffT,
                                                 const float* __restrict__ vbias,
                                                 float* __restrict__ out) {
    __shared__ __align__(16) float hs[64 * 132];
    int n = blockIdx.x / NT2;
    int t = blockIdx.x - n * NT2;
    int l0 = t * T2;
    const float* h2n = h2 + (size_t)n * 64 * L_LEN;
    for (int idx = threadIdx.x; idx < 64 * 130; idx += 256) {
        int ci = idx / 130;
        int j = idx - ci * 130;
        int l = l0 - 1 + j;
        hs[ci * 132 + j] = (l >= 0 && l < L_LEN) ? h2n[(size_t)ci * L_LEN + l] : 0.f;
    }
    __syncthreads();
    int ta = threadIdx.x & 15;
    int tb = threadIdx.x >> 4;
    int k0 = ta * 4;
    int lt = tb * 8;
    float acc[4][8];
#pragma unroll
    for (int kq = 0; kq < 4; ++kq)
#pragma unroll
        for (int m = 0; m < 8; ++m) acc[kq][m] = 0.f;
    const float* wbase = WeffT + (size_t)n * 12288 + k0;
    for (int ci = 0; ci < 64; ++ci) {
        const float* hrow = &hs[ci * 132 + lt];
        float4 wa = *(const float4*)hrow;
        float4 wb = *(const float4*)(hrow + 4);
        float4 wc = *(const float4*)(hrow + 8);
        float win[12] = {wa.x, wa.y, wa.z, wa.w, wb.x, wb.y, wb.z, wb.w,
                         wc.x, wc.y, wc.z, wc.w};
        const float* wp = wbase + ci * 192;
#pragma unroll
        for (int g = 0; g < 3; ++g) {
            float4 wv = *(const float4*)(wp + g * 64);
#pragma unroll
            for (int m = 0; m < 8; ++m) {
                acc[0][m] += wv.x * win[m + g];
                acc[1][m] += wv.y * win[m + g];
                acc[2][m] += wv.z * win[m + g];
                acc[3][m] += wv.w * win[m + g];
            }
        }
    }
    int lbase = l0 + lt;
#pragma unroll
    for (int kq = 0; kq < 4; ++kq) {
        float vb = vbias[n * 64 + k0 + kq];
        float* orow = out + ((size_t)n * 64 + k0 + kq) * L_LEN + lbase;
        if (lbase < L_LEN) {
            float4 s0 = {acc[kq][0] + vb, acc[kq][1] + vb, acc[kq][2] + vb, acc[kq][3] + vb};
            *(float4*)orow = s0;
        }
        if (lbase + 4 < L_LEN) {
            float4 s1 = {acc[kq][4] + vb, acc[kq][5] + vb, acc[kq][6] + vb, acc[kq][7] + vb};
            *(float4*)(orow + 4) = s1;
        }
    }
}

extern "C" void kernel_launch(void* const* d_in, const int* in_sizes, int n_in,
                              void* d_out, int out_size, void* d_ws, size_t ws_size,
                              hipStream_t stream) {
    const float* x  = (const float*)d_in[0];
    const float* w1 = (const float*)d_in[1];
    const float* w2 = (const float*)d_in[2];
    const float* wA = (const float*)d_in[3];
    const float* bA = (const float*)d_in[4];
    float* out = (float*)d_out;
    char* ws = (char*)d_ws;
    const size_t HB = (size_t)64 * 64 * L_LEN * 4;   // 73,728,000 B
    float* h2     = (float*)(ws + HB);
    float* sq     = (float*)(ws + 2 * HB);            // 16 KB
    float* rowsum = (float*)(ws + 2 * HB + 16384);    // 16 KB
    float* w2t    = (float*)(ws + 2 * HB + 32768);    // 80 KB
    // overlays in the first HB region (h1 no longer exists):
    float* Rp    = (float*)ws;                        // 62,914,560 B
    float* Rsum  = (float*)(ws + 62914560);           //  5,242,880 B
    float* coefb = (float*)(ws + 68157440);           //    131,072 B
    float* WeffT = (float*)(ws + 68288512);           //  3,145,728 B
    float* vbias = (float*)(ws + 71434240);           //     16,384 B

    prep_w2t_k<<<80, 256, 0, stream>>>(w2, w2t);
    conv12_k<<<64 * NT2, 256, 0, stream>>>(x, w1, w2t, h2);
    sumstat_k<<<4096, 256, 0, stream>>>(h2, sq, rowsum);
    corr_k<<<64 * KSPL, 256, 0, stream>>>(h2, Rp);
    reduce_k<<<64 * 80, 256, 0, stream>>>(Rp, Rsum);
    mcoef_k<<<64, 256, 0, stream>>>(Rsum, h2, sq, rowsum, wA, bA, coefb);
    weff_k<<<64, 256, 0, stream>>>(coefb, wA, sq, bA, WeffT, vbias);
    outconv_k<<<64 * NT2, 256, 0, stream>>>(h2, WeffT, vbias, out);
}